// Round 16
// baseline (136.506 us; speedup 1.0000x reference)
//
#include <hip/hip_runtime.h>
#include <hip/hip_bf16.h>

typedef __attribute__((ext_vector_type(4))) float f32x4;
typedef __attribute__((ext_vector_type(8))) short bf16x8;
typedef __attribute__((ext_vector_type(2))) unsigned int u32x2;
typedef unsigned short u16;
typedef unsigned int u32;

// ---------- helpers ----------

__device__ __forceinline__ u16 f2bf(float f) {
  union { float f; unsigned int u; } v;
  v.f = f;
  unsigned int r = (v.u + 0x7fffu + ((v.u >> 16) & 1u)) >> 16;
  return (u16)r;
}

// packed f32->bf16 (RNE): u32 = [bf(a) | bf(b)<<16]
__device__ __forceinline__ u32 pk2(float a, float b) {
  u32 r;
  asm("v_cvt_pk_bf16_f32 %0, %1, %2" : "=v"(r) : "v"(a), "v"(b));
  return r;
}

// async global->LDS, 16 bytes/lane; LDS dest = wave-uniform base + lane*16
__device__ __forceinline__ void async16(const void* g, const void* l) {
  __builtin_amdgcn_global_load_lds(
      (const __attribute__((address_space(1))) unsigned int*)(unsigned long)g,
      (__attribute__((address_space(3))) unsigned int*)(unsigned int)(unsigned long)l,
      16, 0, 0);
}

__device__ __forceinline__ void bar() {
  asm volatile("" ::: "memory");
  __builtin_amdgcn_s_barrier();
  asm volatile("" ::: "memory");
}

#define WAIT_VM0() asm volatile("s_waitcnt vmcnt(0)" ::: "memory")

// ===================================================================
// 1) merged converts, 1-D INTERLEAVED grid (z = bid % 24 so transpose
//    and streaming-Q blocks are co-resident from dispatch 0).
// z<16 -> K/V transpose-convert into SLAB layout: per batch
//   [s = n/8 (256 slabs)][c (1024)][n%8] bf16, slab 16 KB. Block reads
//   8 full rows (32 KB contiguous), writes one 16 KB contiguous slab.
//   LDS slot-XOR val = c ^ ((c>>3)&7) -> both b128 phases conflict-free.
// z>=16 -> Q plain convert (pure streaming), batch z-16.
// ===================================================================
__global__ __launch_bounds__(256) void cvt_all(const float* __restrict__ Kin,
                                               const float* __restrict__ Vin,
                                               const float* __restrict__ Q,
                                               u16* __restrict__ Kt,
                                               u16* __restrict__ Vt,
                                               u16* __restrict__ Qb) {
  __shared__ char tile[16384];
  const int bid = blockIdx.x;          // 0..6143
  const int z = bid % 24;              // interleave work types round-robin
  const int x = bid / 24;              // 0..255
  const int t = threadIdx.x;

  if (z < 16) {
    const int bsel = z >> 1;
    const float* in = (z & 1) ? Kin : Vin;
    u16* out = (z & 1) ? Kt : Vt;
    const long bo = (long)bsel * 2048 * 1024;
    const int s = x;                   // slab 0..255
    const float* src = in + bo + (long)s * 8 * 1024;

    // read 8 full rows, thread t covers cols t*4..t*4+3 of each
    f32x4 v[8];
#pragma unroll
    for (int i = 0; i < 8; ++i)
      v[i] = *(const f32x4*)(src + i * 1024 + t * 4);

    // pack per column: 8 n-values -> 16B, swizzled slot write
#pragma unroll
    for (int q = 0; q < 4; ++q) {
      const int c = t * 4 + q;
      const int val = c ^ ((c >> 3) & 7);
      union { u32 w[4]; uint4 u4; } U;
      U.w[0] = pk2(v[0][q], v[1][q]);
      U.w[1] = pk2(v[2][q], v[3][q]);
      U.w[2] = pk2(v[4][q], v[5][q]);
      U.w[3] = pk2(v[6][q], v[7][q]);
      *(uint4*)(tile + ((long)val << 4)) = U.u4;
    }
    __syncthreads();

    // contiguous 16 KB slab writeout (4 KB per pass)
    u16* dst = out + bo + (long)s * 8192;
#pragma unroll
    for (int p = 0; p < 4; ++p) {
      const int u = t + p * 256;
      const int val = u ^ ((u >> 3) & 7);
      uint4 r = *(const uint4*)(tile + ((long)val << 4));
      *(uint4*)(dst + (long)u * 8) = r;
    }
  } else {
    // plain Q convert: 32 KB fp32 chunk -> 16 KB bf16, both streaming
    const int qb = z - 16;
    const float* src = Q + (long)qb * 2048 * 1024 + (long)x * 8192;
    u16* dst = Qb + (long)qb * 2048 * 1024 + (long)x * 8192;
#pragma unroll
    for (int i = 0; i < 8; ++i) {
      f32x4 v = *(const f32x4*)(src + (t + i * 256) * 4);
      u32x2 w; w.x = pk2(v.x, v.y); w.y = pk2(v.z, v.w);
      *(u32x2*)(dst + (long)(t + i * 256) * 4) = w;
    }
  }
}

// ===================================================================
// 2) GEMM A from SLAB operands: Pt[d][h] = sum_n Vt[d][n] * Kt[h][n]
// per batch M=1024(d) N=1024(h) K=2048(n). BM=256, BN=128, BK=64.
// 512 thr = 8 waves (2M x 4N). Slabs [s][c][8n]; contiguous
// global_load_lds staging, linear LDS; drift schedule (1 barrier/K-tile).
// Epilogue: Pt tiled [ht][d][64h].
// ===================================================================
__global__ __launch_bounds__(512, 2) void gemmA(const u16* __restrict__ Vt,
                                                const u16* __restrict__ Kt,
                                                u16* __restrict__ Pt) {
  __shared__ u16 As[2][8][256][8];  // 2 x 32 KB
  __shared__ u16 Bs[2][8][128][8];  // 2 x 16 KB

  const int bid = blockIdx.x;
  const int b = bid & 7;              // batch -> XCD pin
  const int tile = bid >> 3;          // 0..31
  const int bn0 = (tile & 7) * 128;   // h
  const int bm0 = (tile >> 3) * 256;  // d

  const int tid = threadIdx.x;
  const int lane = tid & 63;
  const int wave = tid >> 6;
  const int wr = wave >> 2;  // 0..1 (M)
  const int wc = wave & 3;   // 0..3 (N)
  const int l16 = lane & 15;
  const int kh = lane >> 4;

  const char* Ab = (const char*)(Vt + (long)b * 1024 * 2048);
  const char* Bb = (const char*)(Kt + (long)b * 1024 * 2048);

  int aoff[4], boff[2];
#pragma unroll
  for (int i = 0; i < 4; ++i) {
    int u = tid + i * 512;                        // 0..2047
    aoff[i] = (u >> 8) * 16384 + (bm0 + (u & 255)) * 16;
  }
#pragma unroll
  for (int i = 0; i < 2; ++i) {
    int u = tid + i * 512;                        // 0..1023
    boff[i] = (u >> 7) * 16384 + (bn0 + (u & 127)) * 16;
  }

#define STG_A(buf)                                                             \
  {                                                                            \
    _Pragma("unroll") for (int i_ = 0; i_ < 4; ++i_) {                         \
      async16(Ab + aoff[i_], (char*)&As[buf][0][0][0] + (tid + i_ * 512) * 16);\
      aoff[i_] += 131072;                                                      \
    }                                                                          \
  }
#define STG_B(buf)                                                             \
  {                                                                            \
    _Pragma("unroll") for (int i_ = 0; i_ < 2; ++i_) {                         \
      async16(Bb + boff[i_], (char*)&Bs[buf][0][0][0] + (tid + i_ * 512) * 16);\
      boff[i_] += 131072;                                                      \
    }                                                                          \
  }

  int offA[2][4][2];  // [qm][f][ks]
#pragma unroll
  for (int q = 0; q < 2; ++q)
#pragma unroll
    for (int f = 0; f < 4; ++f)
#pragma unroll
      for (int ks = 0; ks < 2; ++ks)
        offA[q][f][ks] =
            (ks * 4 + kh) * 4096 + (q * 128 + wr * 64 + f * 16 + l16) * 16;
  int offB[2][2];  // [fn][ks]
#pragma unroll
  for (int fn = 0; fn < 2; ++fn)
#pragma unroll
    for (int ks = 0; ks < 2; ++ks)
      offB[fn][ks] = (ks * 4 + kh) * 2048 + (fn * 64 + wc * 16 + l16) * 16;

  f32x4 acc[8][2] = {};
  bf16x8 ar[4][2], br[2][2];

  STG_A(0); STG_B(0);
  WAIT_VM0();
  bar();

  const int NT = 32;
  for (int t = 0; t < NT; ++t) {
    const int cur = t & 1, nxt = cur ^ 1;
    const bool g = (t + 1 < NT);
    const char* Abuf = (const char*)&As[cur][0][0][0];
    const char* Bbuf = (const char*)&Bs[cur][0][0][0];

#pragma unroll
    for (int f = 0; f < 4; ++f)
#pragma unroll
      for (int ks = 0; ks < 2; ++ks)
        ar[f][ks] = *(const bf16x8*)(Abuf + offA[0][f][ks]);
#pragma unroll
    for (int fn = 0; fn < 2; ++fn)
#pragma unroll
      for (int ks = 0; ks < 2; ++ks)
        br[fn][ks] = *(const bf16x8*)(Bbuf + offB[fn][ks]);

    if (g) { STG_A(nxt); STG_B(nxt); }

    __builtin_amdgcn_s_setprio(1);
#pragma unroll
    for (int f = 0; f < 4; ++f)
#pragma unroll
      for (int n = 0; n < 2; ++n)
#pragma unroll
        for (int ks = 0; ks < 2; ++ks)
          acc[f][n] = __builtin_amdgcn_mfma_f32_16x16x32_bf16(
              ar[f][ks], br[n][ks], acc[f][n], 0, 0, 0);
    __builtin_amdgcn_s_setprio(0);

#pragma unroll
    for (int f = 0; f < 4; ++f)
#pragma unroll
      for (int ks = 0; ks < 2; ++ks)
        ar[f][ks] = *(const bf16x8*)(Abuf + offA[1][f][ks]);

    __builtin_amdgcn_s_setprio(1);
#pragma unroll
    for (int f = 0; f < 4; ++f)
#pragma unroll
      for (int n = 0; n < 2; ++n)
#pragma unroll
        for (int ks = 0; ks < 2; ++ks)
          acc[4 + f][n] = __builtin_amdgcn_mfma_f32_16x16x32_bf16(
              ar[f][ks], br[n][ks], acc[4 + f][n], 0, 0, 0);
    __builtin_amdgcn_s_setprio(0);

    if (g) WAIT_VM0();
    bar();
  }
#undef STG_A
#undef STG_B

  u16* Cb = Pt + (long)b * 1024 * 1024;
#pragma unroll
  for (int fm = 0; fm < 8; ++fm) {
    const int gm = bm0 + (fm >> 2) * 128 + wr * 64 + (fm & 3) * 16 + kh * 4;
#pragma unroll
    for (int fn = 0; fn < 2; ++fn) {
#pragma unroll
      for (int r = 0; r < 4; ++r)
        Cb[(long)((bn0 >> 6) + fn) * 65536 + (long)(gm + r) * 64 +
           wc * 16 + l16] = f2bf(acc[fm][fn][r]);
    }
  }
}

// ===================================================================
// 3) GEMM B: out[m][d] = sum_h Qb[m][h] * Pt[d][h]
// Qb linear (rowbytes 2048, step 128), Pt tiled slabs (rowbytes 128,
// step 131072). BM=256, BN=128, BK=64, 512 thr; drift schedule.
// ===================================================================
__global__ __launch_bounds__(512, 2) void gemmB(const u16* __restrict__ A,
                                                const u16* __restrict__ Bt,
                                                float* __restrict__ out) {
  __shared__ u16 As[2][256][64];  // 64 KB
  __shared__ u16 Bs[2][128][64];  // 32 KB

  const int bid = blockIdx.x;
  const int b = bid & 7;              // batch -> XCD pin
  const int tile = bid >> 3;          // 0..63
  const int bn0 = (tile & 7) * 128;   // d
  const int bm0 = (tile >> 3) * 256;  // m

  const int tid = threadIdx.x;
  const int lane = tid & 63;
  const int wave = tid >> 6;
  const int wr = wave >> 2;  // 0..1 (M)
  const int wc = wave & 3;   // 0..3 (N)
  const int l16 = lane & 15;
  const int kh = lane >> 4;

  const char* Ab = (const char*)(A + (long)b * 2048 * 1024);
  const char* Bb = (const char*)(Bt + (long)b * 1024 * 1024);

  int aoff[4], boff[2];
#pragma unroll
  for (int i = 0; i < 4; ++i) {
    int u = tid + i * 512;
    int row = u >> 3, sl = (u & 7) ^ (row & 7);
    aoff[i] = (bm0 + row) * 2048 + sl * 16;       // Qb linear
  }
#pragma unroll
  for (int i = 0; i < 2; ++i) {
    int u = tid + i * 512;
    int row = u >> 3, sl = (u & 7) ^ (row & 7);
    boff[i] = (bn0 + row) * 128 + sl * 16;        // Pt tiled
  }

#define STG_A(buf)                                                          \
  {                                                                         \
    _Pragma("unroll") for (int i_ = 0; i_ < 4; ++i_) {                      \
      async16(Ab + aoff[i_], (char*)&As[buf][0][0] + (tid + i_ * 512) * 16);\
      aoff[i_] += 128;                                                      \
    }                                                                       \
  }
#define STG_B(buf)                                                          \
  {                                                                         \
    _Pragma("unroll") for (int i_ = 0; i_ < 2; ++i_) {                      \
      async16(Bb + boff[i_], (char*)&Bs[buf][0][0] + (tid + i_ * 512) * 16);\
      boff[i_] += 131072;                                                   \
    }                                                                       \
  }

  int offA[2][4][2];
#pragma unroll
  for (int q = 0; q < 2; ++q)
#pragma unroll
    for (int f = 0; f < 4; ++f) {
      int r = q * 128 + wr * 64 + f * 16 + l16;
#pragma unroll
      for (int ks = 0; ks < 2; ++ks)
        offA[q][f][ks] = r * 64 + (((ks * 4 + kh) ^ (l16 & 7)) * 8);
    }
  int offB[2][2];
#pragma unroll
  for (int fn = 0; fn < 2; ++fn) {
    int r = fn * 64 + wc * 16 + l16;
#pragma unroll
    for (int ks = 0; ks < 2; ++ks)
      offB[fn][ks] = r * 64 + (((ks * 4 + kh) ^ (l16 & 7)) * 8);
  }

  f32x4 acc[8][2] = {};
  bf16x8 ar[4][2], br[2][2];

  STG_A(0); STG_B(0);
  WAIT_VM0();
  bar();

  const int NT = 16;
  for (int t = 0; t < NT; ++t) {
    const int cur = t & 1, nxt = cur ^ 1;
    const bool g = (t + 1 < NT);
    const u16* Abuf = &As[cur][0][0];
    const u16* Bbuf = &Bs[cur][0][0];

#pragma unroll
    for (int f = 0; f < 4; ++f)
#pragma unroll
      for (int ks = 0; ks < 2; ++ks)
        ar[f][ks] = *(const bf16x8*)(Abuf + offA[0][f][ks]);
#pragma unroll
    for (int fn = 0; fn < 2; ++fn)
#pragma unroll
      for (int ks = 0; ks < 2; ++ks)
        br[fn][ks] = *(const bf16x8*)(Bbuf + offB[fn][ks]);

    if (g) { STG_A(nxt); STG_B(nxt); }

    __builtin_amdgcn_s_setprio(1);
#pragma unroll
    for (int f = 0; f < 4; ++f)
#pragma unroll
      for (int n = 0; n < 2; ++n)
#pragma unroll
        for (int ks = 0; ks < 2; ++ks)
          acc[f][n] = __builtin_amdgcn_mfma_f32_16x16x32_bf16(
              ar[f][ks], br[n][ks], acc[f][n], 0, 0, 0);
    __builtin_amdgcn_s_setprio(0);

#pragma unroll
    for (int f = 0; f < 4; ++f)
#pragma unroll
      for (int ks = 0; ks < 2; ++ks)
        ar[f][ks] = *(const bf16x8*)(Abuf + offA[1][f][ks]);

    __builtin_amdgcn_s_setprio(1);
#pragma unroll
    for (int f = 0; f < 4; ++f)
#pragma unroll
      for (int n = 0; n < 2; ++n)
#pragma unroll
        for (int ks = 0; ks < 2; ++ks)
          acc[4 + f][n] = __builtin_amdgcn_mfma_f32_16x16x32_bf16(
              ar[f][ks], br[n][ks], acc[4 + f][n], 0, 0, 0);
    __builtin_amdgcn_s_setprio(0);

    if (g) WAIT_VM0();
    bar();
  }
#undef STG_A
#undef STG_B

  float* Cf = out + (long)b * 2048 * 1024;
#pragma unroll
  for (int fm = 0; fm < 8; ++fm) {
    const int gm = bm0 + (fm >> 2) * 128 + wr * 64 + (fm & 3) * 16 + kh * 4;
#pragma unroll
    for (int fn = 0; fn < 2; ++fn) {
      const int gn = bn0 + fn * 64 + wc * 16 + l16;
#pragma unroll
      for (int r = 0; r < 4; ++r)
        Cf[(long)(gm + r) * 1024 + gn] = acc[fm][fn][r];
    }
  }
}

// ---------- launch ----------

extern "C" void kernel_launch(void* const* d_in, const int* in_sizes, int n_in,
                              void* d_out, int out_size, void* d_ws, size_t ws_size,
                              hipStream_t stream) {
  const float* Q  = (const float*)d_in[0];
  const float* Kf = (const float*)d_in[1];
  // d_in[2] = span   (unused by the reference's returned value)
  const float* V  = (const float*)d_in[3];
  // d_in[4] = key_pe (unused)
  float* out = (float*)d_out;

  // workspace: Vt 32MB (slab), Kt 32MB (slab), Pt 16MB (tiled), Qb 32MB (linear)
  char* ws = (char*)d_ws;
  u16* Vt = (u16*)(ws);
  u16* Kt = (u16*)(ws + (size_t)32 * 1024 * 1024);
  u16* Pt = (u16*)(ws + (size_t)64 * 1024 * 1024);
  u16* Qb = (u16*)(ws + (size_t)80 * 1024 * 1024);

  // 1) all converts, one kernel, interleaved work types (6144 blocks)
  cvt_all<<<6144, 256, 0, stream>>>(Kf, V, Q, Kt, Vt, Qb);

  // 2) GEMM A: Pt[d][h] = sum_n Vt[d][n]*Kt[h][n]; 256 blocks
  gemmA<<<256, 512, 0, stream>>>(Vt, Kt, Pt);

  // 3) GEMM B: out[m][d] = sum_h Qb[m][h]*Pt[d][h]; 512 blocks
  gemmB<<<512, 512, 0, stream>>>(Qb, Pt, out);
}

// Round 17
// 130.776 us; speedup vs baseline: 1.0438x; 1.0438x over previous
//
#include <hip/hip_runtime.h>
#include <hip/hip_bf16.h>

typedef __attribute__((ext_vector_type(4))) float f32x4;
typedef __attribute__((ext_vector_type(8))) short bf16x8;
typedef __attribute__((ext_vector_type(2))) unsigned int u32x2;
typedef unsigned short u16;
typedef unsigned int u32;

// ---------- helpers ----------

__device__ __forceinline__ u16 f2bf(float f) {
  union { float f; unsigned int u; } v;
  v.f = f;
  unsigned int r = (v.u + 0x7fffu + ((v.u >> 16) & 1u)) >> 16;
  return (u16)r;
}

// packed f32->bf16 (RNE): u32 = [bf(a) | bf(b)<<16]
__device__ __forceinline__ u32 pk2(float a, float b) {
  u32 r;
  asm("v_cvt_pk_bf16_f32 %0, %1, %2" : "=v"(r) : "v"(a), "v"(b));
  return r;
}

// async global->LDS, 16 bytes/lane; LDS dest = wave-uniform base + lane*16
__device__ __forceinline__ void async16(const void* g, const void* l) {
  __builtin_amdgcn_global_load_lds(
      (const __attribute__((address_space(1))) unsigned int*)(unsigned long)g,
      (__attribute__((address_space(3))) unsigned int*)(unsigned int)(unsigned long)l,
      16, 0, 0);
}

__device__ __forceinline__ void bar() {
  asm volatile("" ::: "memory");
  __builtin_amdgcn_s_barrier();
  asm volatile("" ::: "memory");
}

#define WAIT_VM0() asm volatile("s_waitcnt vmcnt(0)" ::: "memory")

// ===================================================================
// 1) merged converts (measured-best: 2-D grid, x-fastest slab walk for
//    sequential DRAM locality; transpose and Q-stream blocks co-resident
//    via the y-dim interleaving of the dispatch walk).
// z = blockIdx.y < 16 -> K/V transpose-convert into SLAB layout:
//   per batch [s = n/8 (256 slabs)][c (1024)][n%8] bf16, slab 16 KB.
//   Block reads 8 full rows (32 KB contiguous), writes one 16 KB
//   contiguous slab. LDS slot-XOR val = c ^ ((c>>3)&7): both b128
//   phases conflict-free.
// z >= 16 -> Q plain convert (pure streaming), batch z-16.
// ===================================================================
__global__ __launch_bounds__(256) void cvt_all(const float* __restrict__ Kin,
                                               const float* __restrict__ Vin,
                                               const float* __restrict__ Q,
                                               u16* __restrict__ Kt,
                                               u16* __restrict__ Vt,
                                               u16* __restrict__ Qb) {
  __shared__ char tile[16384];
  const int z = blockIdx.y;
  const int t = threadIdx.x;

  if (z < 16) {
    const int bsel = z >> 1;
    const float* in = (z & 1) ? Kin : Vin;
    u16* out = (z & 1) ? Kt : Vt;
    const long bo = (long)bsel * 2048 * 1024;
    const int s = blockIdx.x;                       // slab 0..255
    const float* src = in + bo + (long)s * 8 * 1024;

    // read 8 full rows, thread t covers cols t*4..t*4+3 of each
    f32x4 v[8];
#pragma unroll
    for (int i = 0; i < 8; ++i)
      v[i] = *(const f32x4*)(src + i * 1024 + t * 4);

    // pack per column: 8 n-values -> 16B, swizzled slot write
#pragma unroll
    for (int q = 0; q < 4; ++q) {
      const int c = t * 4 + q;
      const int val = c ^ ((c >> 3) & 7);
      union { u32 w[4]; uint4 u4; } U;
      U.w[0] = pk2(v[0][q], v[1][q]);
      U.w[1] = pk2(v[2][q], v[3][q]);
      U.w[2] = pk2(v[4][q], v[5][q]);
      U.w[3] = pk2(v[6][q], v[7][q]);
      *(uint4*)(tile + ((long)val << 4)) = U.u4;
    }
    __syncthreads();

    // contiguous 16 KB slab writeout (4 KB per pass)
    u16* dst = out + bo + (long)s * 8192;
#pragma unroll
    for (int p = 0; p < 4; ++p) {
      const int u = t + p * 256;
      const int val = u ^ ((u >> 3) & 7);
      uint4 r = *(const uint4*)(tile + ((long)val << 4));
      *(uint4*)(dst + (long)u * 8) = r;
    }
  } else {
    // plain Q convert: 32 KB fp32 chunk -> 16 KB bf16, both streaming
    const int qb = z - 16;
    const float* src = Q + (long)qb * 2048 * 1024 + (long)blockIdx.x * 8192;
    u16* dst = Qb + (long)qb * 2048 * 1024 + (long)blockIdx.x * 8192;
#pragma unroll
    for (int i = 0; i < 8; ++i) {
      f32x4 v = *(const f32x4*)(src + (t + i * 256) * 4);
      u32x2 w; w.x = pk2(v.x, v.y); w.y = pk2(v.z, v.w);
      *(u32x2*)(dst + (long)(t + i * 256) * 4) = w;
    }
  }
}

// ===================================================================
// 2) GEMM A from SLAB operands: Pt[d][h] = sum_n Vt[d][n] * Kt[h][n]
// per batch M=1024(d) N=1024(h) K=2048(n). BM=256, BN=128, BK=64.
// 512 thr = 8 waves (2M x 4N). Slabs [s][c][8n]; contiguous
// global_load_lds staging, linear LDS; drift schedule (1 barrier/K-tile).
// Epilogue: Pt tiled [ht][d][64h].
// ===================================================================
__global__ __launch_bounds__(512, 2) void gemmA(const u16* __restrict__ Vt,
                                                const u16* __restrict__ Kt,
                                                u16* __restrict__ Pt) {
  __shared__ u16 As[2][8][256][8];  // 2 x 32 KB
  __shared__ u16 Bs[2][8][128][8];  // 2 x 16 KB

  const int bid = blockIdx.x;
  const int b = bid & 7;              // batch -> XCD pin
  const int tile = bid >> 3;          // 0..31
  const int bn0 = (tile & 7) * 128;   // h
  const int bm0 = (tile >> 3) * 256;  // d

  const int tid = threadIdx.x;
  const int lane = tid & 63;
  const int wave = tid >> 6;
  const int wr = wave >> 2;  // 0..1 (M)
  const int wc = wave & 3;   // 0..3 (N)
  const int l16 = lane & 15;
  const int kh = lane >> 4;

  const char* Ab = (const char*)(Vt + (long)b * 1024 * 2048);
  const char* Bb = (const char*)(Kt + (long)b * 1024 * 2048);

  int aoff[4], boff[2];
#pragma unroll
  for (int i = 0; i < 4; ++i) {
    int u = tid + i * 512;                        // 0..2047
    aoff[i] = (u >> 8) * 16384 + (bm0 + (u & 255)) * 16;
  }
#pragma unroll
  for (int i = 0; i < 2; ++i) {
    int u = tid + i * 512;                        // 0..1023
    boff[i] = (u >> 7) * 16384 + (bn0 + (u & 127)) * 16;
  }

#define STG_A(buf)                                                             \
  {                                                                            \
    _Pragma("unroll") for (int i_ = 0; i_ < 4; ++i_) {                         \
      async16(Ab + aoff[i_], (char*)&As[buf][0][0][0] + (tid + i_ * 512) * 16);\
      aoff[i_] += 131072;                                                      \
    }                                                                          \
  }
#define STG_B(buf)                                                             \
  {                                                                            \
    _Pragma("unroll") for (int i_ = 0; i_ < 2; ++i_) {                         \
      async16(Bb + boff[i_], (char*)&Bs[buf][0][0][0] + (tid + i_ * 512) * 16);\
      boff[i_] += 131072;                                                      \
    }                                                                          \
  }

  int offA[2][4][2];  // [qm][f][ks]
#pragma unroll
  for (int q = 0; q < 2; ++q)
#pragma unroll
    for (int f = 0; f < 4; ++f)
#pragma unroll
      for (int ks = 0; ks < 2; ++ks)
        offA[q][f][ks] =
            (ks * 4 + kh) * 4096 + (q * 128 + wr * 64 + f * 16 + l16) * 16;
  int offB[2][2];  // [fn][ks]
#pragma unroll
  for (int fn = 0; fn < 2; ++fn)
#pragma unroll
    for (int ks = 0; ks < 2; ++ks)
      offB[fn][ks] = (ks * 4 + kh) * 2048 + (fn * 64 + wc * 16 + l16) * 16;

  f32x4 acc[8][2] = {};
  bf16x8 ar[4][2], br[2][2];

  STG_A(0); STG_B(0);
  WAIT_VM0();
  bar();

  const int NT = 32;
  for (int t = 0; t < NT; ++t) {
    const int cur = t & 1, nxt = cur ^ 1;
    const bool g = (t + 1 < NT);
    const char* Abuf = (const char*)&As[cur][0][0][0];
    const char* Bbuf = (const char*)&Bs[cur][0][0][0];

#pragma unroll
    for (int f = 0; f < 4; ++f)
#pragma unroll
      for (int ks = 0; ks < 2; ++ks)
        ar[f][ks] = *(const bf16x8*)(Abuf + offA[0][f][ks]);
#pragma unroll
    for (int fn = 0; fn < 2; ++fn)
#pragma unroll
      for (int ks = 0; ks < 2; ++ks)
        br[fn][ks] = *(const bf16x8*)(Bbuf + offB[fn][ks]);

    if (g) { STG_A(nxt); STG_B(nxt); }

    __builtin_amdgcn_s_setprio(1);
#pragma unroll
    for (int f = 0; f < 4; ++f)
#pragma unroll
      for (int n = 0; n < 2; ++n)
#pragma unroll
        for (int ks = 0; ks < 2; ++ks)
          acc[f][n] = __builtin_amdgcn_mfma_f32_16x16x32_bf16(
              ar[f][ks], br[n][ks], acc[f][n], 0, 0, 0);
    __builtin_amdgcn_s_setprio(0);

#pragma unroll
    for (int f = 0; f < 4; ++f)
#pragma unroll
      for (int ks = 0; ks < 2; ++ks)
        ar[f][ks] = *(const bf16x8*)(Abuf + offA[1][f][ks]);

    __builtin_amdgcn_s_setprio(1);
#pragma unroll
    for (int f = 0; f < 4; ++f)
#pragma unroll
      for (int n = 0; n < 2; ++n)
#pragma unroll
        for (int ks = 0; ks < 2; ++ks)
          acc[4 + f][n] = __builtin_amdgcn_mfma_f32_16x16x32_bf16(
              ar[f][ks], br[n][ks], acc[4 + f][n], 0, 0, 0);
    __builtin_amdgcn_s_setprio(0);

    if (g) WAIT_VM0();
    bar();
  }
#undef STG_A
#undef STG_B

  u16* Cb = Pt + (long)b * 1024 * 1024;
#pragma unroll
  for (int fm = 0; fm < 8; ++fm) {
    const int gm = bm0 + (fm >> 2) * 128 + wr * 64 + (fm & 3) * 16 + kh * 4;
#pragma unroll
    for (int fn = 0; fn < 2; ++fn) {
#pragma unroll
      for (int r = 0; r < 4; ++r)
        Cb[(long)((bn0 >> 6) + fn) * 65536 + (long)(gm + r) * 64 +
           wc * 16 + l16] = f2bf(acc[fm][fn][r]);
    }
  }
}

// ===================================================================
// 3) GEMM B: out[m][d] = sum_h Qb[m][h] * Pt[d][h]
// Qb linear (rowbytes 2048, step 128), Pt tiled slabs (rowbytes 128,
// step 131072). BM=256, BN=128, BK=64, 512 thr; drift schedule.
// ===================================================================
__global__ __launch_bounds__(512, 2) void gemmB(const u16* __restrict__ A,
                                                const u16* __restrict__ Bt,
                                                float* __restrict__ out) {
  __shared__ u16 As[2][256][64];  // 64 KB
  __shared__ u16 Bs[2][128][64];  // 32 KB

  const int bid = blockIdx.x;
  const int b = bid & 7;              // batch -> XCD pin
  const int tile = bid >> 3;          // 0..63
  const int bn0 = (tile & 7) * 128;   // d
  const int bm0 = (tile >> 3) * 256;  // m

  const int tid = threadIdx.x;
  const int lane = tid & 63;
  const int wave = tid >> 6;
  const int wr = wave >> 2;  // 0..1 (M)
  const int wc = wave & 3;   // 0..3 (N)
  const int l16 = lane & 15;
  const int kh = lane >> 4;

  const char* Ab = (const char*)(A + (long)b * 2048 * 1024);
  const char* Bb = (const char*)(Bt + (long)b * 1024 * 1024);

  int aoff[4], boff[2];
#pragma unroll
  for (int i = 0; i < 4; ++i) {
    int u = tid + i * 512;
    int row = u >> 3, sl = (u & 7) ^ (row & 7);
    aoff[i] = (bm0 + row) * 2048 + sl * 16;       // Qb linear
  }
#pragma unroll
  for (int i = 0; i < 2; ++i) {
    int u = tid + i * 512;
    int row = u >> 3, sl = (u & 7) ^ (row & 7);
    boff[i] = (bn0 + row) * 128 + sl * 16;        // Pt tiled
  }

#define STG_A(buf)                                                          \
  {                                                                         \
    _Pragma("unroll") for (int i_ = 0; i_ < 4; ++i_) {                      \
      async16(Ab + aoff[i_], (char*)&As[buf][0][0] + (tid + i_ * 512) * 16);\
      aoff[i_] += 128;                                                      \
    }                                                                       \
  }
#define STG_B(buf)                                                          \
  {                                                                         \
    _Pragma("unroll") for (int i_ = 0; i_ < 2; ++i_) {                      \
      async16(Bb + boff[i_], (char*)&Bs[buf][0][0] + (tid + i_ * 512) * 16);\
      boff[i_] += 131072;                                                   \
    }                                                                       \
  }

  int offA[2][4][2];
#pragma unroll
  for (int q = 0; q < 2; ++q)
#pragma unroll
    for (int f = 0; f < 4; ++f) {
      int r = q * 128 + wr * 64 + f * 16 + l16;
#pragma unroll
      for (int ks = 0; ks < 2; ++ks)
        offA[q][f][ks] = r * 64 + (((ks * 4 + kh) ^ (l16 & 7)) * 8);
    }
  int offB[2][2];
#pragma unroll
  for (int fn = 0; fn < 2; ++fn) {
    int r = fn * 64 + wc * 16 + l16;
#pragma unroll
    for (int ks = 0; ks < 2; ++ks)
      offB[fn][ks] = r * 64 + (((ks * 4 + kh) ^ (l16 & 7)) * 8);
  }

  f32x4 acc[8][2] = {};
  bf16x8 ar[4][2], br[2][2];

  STG_A(0); STG_B(0);
  WAIT_VM0();
  bar();

  const int NT = 16;
  for (int t = 0; t < NT; ++t) {
    const int cur = t & 1, nxt = cur ^ 1;
    const bool g = (t + 1 < NT);
    const u16* Abuf = &As[cur][0][0];
    const u16* Bbuf = &Bs[cur][0][0];

#pragma unroll
    for (int f = 0; f < 4; ++f)
#pragma unroll
      for (int ks = 0; ks < 2; ++ks)
        ar[f][ks] = *(const bf16x8*)(Abuf + offA[0][f][ks]);
#pragma unroll
    for (int fn = 0; fn < 2; ++fn)
#pragma unroll
      for (int ks = 0; ks < 2; ++ks)
        br[fn][ks] = *(const bf16x8*)(Bbuf + offB[fn][ks]);

    if (g) { STG_A(nxt); STG_B(nxt); }

    __builtin_amdgcn_s_setprio(1);
#pragma unroll
    for (int f = 0; f < 4; ++f)
#pragma unroll
      for (int n = 0; n < 2; ++n)
#pragma unroll
        for (int ks = 0; ks < 2; ++ks)
          acc[f][n] = __builtin_amdgcn_mfma_f32_16x16x32_bf16(
              ar[f][ks], br[n][ks], acc[f][n], 0, 0, 0);
    __builtin_amdgcn_s_setprio(0);

#pragma unroll
    for (int f = 0; f < 4; ++f)
#pragma unroll
      for (int ks = 0; ks < 2; ++ks)
        ar[f][ks] = *(const bf16x8*)(Abuf + offA[1][f][ks]);

    __builtin_amdgcn_s_setprio(1);
#pragma unroll
    for (int f = 0; f < 4; ++f)
#pragma unroll
      for (int n = 0; n < 2; ++n)
#pragma unroll
        for (int ks = 0; ks < 2; ++ks)
          acc[4 + f][n] = __builtin_amdgcn_mfma_f32_16x16x32_bf16(
              ar[f][ks], br[n][ks], acc[4 + f][n], 0, 0, 0);
    __builtin_amdgcn_s_setprio(0);

    if (g) WAIT_VM0();
    bar();
  }
#undef STG_A
#undef STG_B

  float* Cf = out + (long)b * 2048 * 1024;
#pragma unroll
  for (int fm = 0; fm < 8; ++fm) {
    const int gm = bm0 + (fm >> 2) * 128 + wr * 64 + (fm & 3) * 16 + kh * 4;
#pragma unroll
    for (int fn = 0; fn < 2; ++fn) {
      const int gn = bn0 + fn * 64 + wc * 16 + l16;
#pragma unroll
      for (int r = 0; r < 4; ++r)
        Cf[(long)(gm + r) * 1024 + gn] = acc[fm][fn][r];
    }
  }
}

// ---------- launch ----------

extern "C" void kernel_launch(void* const* d_in, const int* in_sizes, int n_in,
                              void* d_out, int out_size, void* d_ws, size_t ws_size,
                              hipStream_t stream) {
  const float* Q  = (const float*)d_in[0];
  const float* Kf = (const float*)d_in[1];
  // d_in[2] = span   (unused by the reference's returned value)
  const float* V  = (const float*)d_in[3];
  // d_in[4] = key_pe (unused)
  float* out = (float*)d_out;

  // workspace: Vt 32MB (slab), Kt 32MB (slab), Pt 16MB (tiled), Qb 32MB (linear)
  char* ws = (char*)d_ws;
  u16* Vt = (u16*)(ws);
  u16* Kt = (u16*)(ws + (size_t)32 * 1024 * 1024);
  u16* Pt = (u16*)(ws + (size_t)64 * 1024 * 1024);
  u16* Qb = (u16*)(ws + (size_t)80 * 1024 * 1024);

  // 1) all converts in one kernel: z<16 K/V transpose->slab, z>=16 Q plain
  cvt_all<<<dim3(256, 24), 256, 0, stream>>>(Kf, V, Q, Kt, Vt, Qb);

  // 2) GEMM A: Pt[d][h] = sum_n Vt[d][n]*Kt[h][n]; 256 blocks
  gemmA<<<256, 512, 0, stream>>>(Vt, Kt, Pt);

  // 3) GEMM B: out[m][d] = sum_h Qb[m][h]*Pt[d][h]; 512 blocks
  gemmB<<<512, 512, 0, stream>>>(Qb, Pt, out);
}